// Round 1
// baseline (21575.623 us; speedup 1.0000x reference)
//
#include <hip/hip_runtime.h>
#include <hip/hip_bf16.h>

// Problem constants (from reference): N=100000, F=128, O=128, S=4, B=2, E=3200000
#define NN 100000
#define FF 128
#define OO 128
#define SS 4
#define BBASES 2
#define EE 3200000

// ---------------------------------------------------------------------------
// V[s] = sum_b W_comp[s,b] * W[b]   -> [S, F, O]   (65536 elements, trivial)
// ---------------------------------------------------------------------------
__global__ void compute_V_kernel(const float* __restrict__ W,
                                 const float* __restrict__ Wc,
                                 float* __restrict__ V) {
  int i = blockIdx.x * blockDim.x + threadIdx.x;  // over S*F*O = 65536
  int s = i >> 14;                                // F*O = 16384
  int fo = i & 16383;
  V[i] = Wc[s * BBASES + 0] * W[fo] + Wc[s * BBASES + 1] * W[16384 + fo];
}

// ---------------------------------------------------------------------------
// agg[row] += val * features[col]  for each edge (one support).
// Half-wave (32 lanes) per edge; lane q handles floats 4q..4q+3 (float4).
// ---------------------------------------------------------------------------
__global__ __launch_bounds__(256) void scatter_kernel(
    const float* __restrict__ feat,
    const int* __restrict__ rows,
    const int* __restrict__ cols,
    const float* __restrict__ vals,
    float* __restrict__ agg) {
  int t = blockIdx.x * blockDim.x + threadIdx.x;
  int e = t >> 5;
  int q = t & 31;
  if (e >= EE) return;
  int r = rows[e];
  int c = cols[e];
  float v = vals[e];
  const float4 x =
      *reinterpret_cast<const float4*>(&feat[(size_t)c * FF + q * 4]);
  float* dst = &agg[(size_t)r * FF + q * 4];
  unsafeAtomicAdd(dst + 0, v * x.x);
  unsafeAtomicAdd(dst + 1, v * x.y);
  unsafeAtomicAdd(dst + 2, v * x.z);
  unsafeAtomicAdd(dst + 3, v * x.w);
}

// ---------------------------------------------------------------------------
// C += A @ Bv : A = agg [M][128], Bv = V_s [128][128], C = out_pre [M][128]
// Block tile 64x128, BK=16, 256 threads, 8x4 micro-tile per thread (f32 VALU).
// ---------------------------------------------------------------------------
__global__ __launch_bounds__(256) void gemm_acc_kernel(
    const float* __restrict__ A,
    const float* __restrict__ Bv,
    float* __restrict__ C) {
  __shared__ float As[16][64];    // k-major A tile (4 KB)
  __shared__ float Bs[16][128];   // B tile (8 KB)
  const int tid = threadIdx.x;
  const int bm0 = blockIdx.x * 64;
  const int tx = tid & 31;   // cols tx*4 .. tx*4+3
  const int ty = tid >> 5;   // rows ty*8 .. ty*8+7

  float acc[8][4];
#pragma unroll
  for (int r = 0; r < 8; ++r)
#pragma unroll
    for (int c = 0; c < 4; ++c) acc[r][c] = 0.0f;

  const int ar = tid >> 2;   // 0..63 : row within tile
  const int akq = tid & 3;   // 0..3  : k-quad

  for (int k0 = 0; k0 < FF; k0 += 16) {
    // Load A tile: 64 rows x 16 k (float4 per thread)
    {
      int row = bm0 + ar;
      float4 av = make_float4(0.f, 0.f, 0.f, 0.f);
      if (row < NN)
        av = *reinterpret_cast<const float4*>(
            &A[(size_t)row * FF + k0 + akq * 4]);
      As[akq * 4 + 0][ar] = av.x;
      As[akq * 4 + 1][ar] = av.y;
      As[akq * 4 + 2][ar] = av.z;
      As[akq * 4 + 3][ar] = av.w;
    }
    // Load B tile: 16 x 128 = 512 float4, 2 per thread, fully coalesced
#pragma unroll
    for (int i = 0; i < 2; ++i) {
      int v = tid + i * 256;
      int kk = v >> 5;
      int cq = v & 31;
      *reinterpret_cast<float4*>(&Bs[kk][cq * 4]) =
          *reinterpret_cast<const float4*>(&Bv[(k0 + kk) * OO + cq * 4]);
    }
    __syncthreads();
#pragma unroll
    for (int kk = 0; kk < 16; ++kk) {
      float4 b = *reinterpret_cast<const float4*>(&Bs[kk][tx * 4]);
#pragma unroll
      for (int r = 0; r < 8; ++r) {
        float a = As[kk][ty * 8 + r];
        acc[r][0] += a * b.x;
        acc[r][1] += a * b.y;
        acc[r][2] += a * b.z;
        acc[r][3] += a * b.w;
      }
    }
    __syncthreads();
  }

#pragma unroll
  for (int r = 0; r < 8; ++r) {
    int row = bm0 + ty * 8 + r;
    if (row < NN) {
      float4* cp = reinterpret_cast<float4*>(&C[(size_t)row * OO + tx * 4]);
      float4 c = *cp;
      c.x += acc[r][0];
      c.y += acc[r][1];
      c.z += acc[r][2];
      c.w += acc[r][3];
      *cp = c;
    }
  }
}

// ---------------------------------------------------------------------------
// out = tanh(out), vectorized float4 (12.8M floats = 3.2M float4)
// ---------------------------------------------------------------------------
__global__ __launch_bounds__(256) void tanh_kernel(float* __restrict__ out) {
  int i = blockIdx.x * blockDim.x + threadIdx.x;
  float4* p = reinterpret_cast<float4*>(out) + i;
  float4 v = *p;
  v.x = tanhf(v.x);
  v.y = tanhf(v.y);
  v.z = tanhf(v.z);
  v.w = tanhf(v.w);
  *p = v;
}

extern "C" void kernel_launch(void* const* d_in, const int* in_sizes, int n_in,
                              void* d_out, int out_size, void* d_ws,
                              size_t ws_size, hipStream_t stream) {
  const float* feat = (const float*)d_in[0];   // [N, F]
  const float* W = (const float*)d_in[1];      // [B, F, O]
  const float* Wc = (const float*)d_in[2];     // [S, B]
  const int* erows = (const int*)d_in[3];      // [S, E]
  const int* ecols = (const int*)d_in[4];      // [S, E]
  const float* evals = (const float*)d_in[5];  // [S, E]
  float* out = (float*)d_out;                  // [N, O] f32

  // Workspace layout: V [S*F*O] floats | agg [N*F] floats  (~49.4 MiB total)
  float* V = (float*)d_ws;
  float* agg = V + (size_t)SS * FF * OO;

  compute_V_kernel<<<(SS * FF * OO) / 256, 256, 0, stream>>>(W, Wc, V);
  hipMemsetAsync(out, 0, (size_t)NN * OO * sizeof(float), stream);

  for (int s = 0; s < SS; ++s) {
    hipMemsetAsync(agg, 0, (size_t)NN * FF * sizeof(float), stream);
    scatter_kernel<<<(EE * 32) / 256, 256, 0, stream>>>(
        feat, erows + (size_t)s * EE, ecols + (size_t)s * EE,
        evals + (size_t)s * EE, agg);
    gemm_acc_kernel<<<(NN + 63) / 64, 256, 0, stream>>>(
        agg, V + (size_t)s * FF * OO, out);
  }

  tanh_kernel<<<(NN * OO / 4) / 256, 256, 0, stream>>>(out);
}

// Round 2
// 18881.564 us; speedup vs baseline: 1.1427x; 1.1427x over previous
//
#include <hip/hip_runtime.h>
#include <hip/hip_bf16.h>

// Problem constants: N=100000, F=128, O=128, S=4, B=2, E=3200000
#define NN 100000
#define FF 128
#define OO 128
#define SS 4
#define BBASES 2
#define EE 3200000
#define TOTE (SS * EE)               // 12.8M edges total
#define RR 64                        // dest rows per bin
#define NBINS ((NN + RR - 1) / RR)   // 1563
#define RBLOCKS 512                  // blocks for hist/reorder

// ===========================================================================
// NEW PATH: bin-by-destination + LDS-atomic accumulate + fused GEMM/tanh
// out[n] = tanh( G0[n] @ W0 + G1[n] @ W1 ),  G_b[n] = sum_s Wc[s,b] * sum_{e: row=n} val_e * feat[col_e]
// ===========================================================================

// ---- histogram of edges per bin (block-local LDS hist, then flush) --------
__global__ __launch_bounds__(256) void hist_kernel(const int* __restrict__ rows,
                                                   unsigned int* __restrict__ hist) {
  __shared__ unsigned int lh[NBINS];
  for (int i = threadIdx.x; i < NBINS; i += 256) lh[i] = 0;
  __syncthreads();
  const int stride = gridDim.x * 256;
  for (int i = blockIdx.x * 256 + threadIdx.x; i < TOTE; i += stride)
    atomicAdd(&lh[((unsigned)rows[i]) >> 6], 1u);
  __syncthreads();
  for (int i = threadIdx.x; i < NBINS; i += 256) {
    unsigned int c = lh[i];
    if (c) atomicAdd(&hist[i], c);
  }
}

// ---- exclusive scan over NBINS (single block) -----------------------------
__global__ __launch_bounds__(256) void scan_kernel(const unsigned int* __restrict__ hist,
                                                   unsigned int* __restrict__ bin_start,
                                                   unsigned int* __restrict__ cursor) {
  __shared__ unsigned int sums[256];
  const int C = (NBINS + 255) / 256;  // 7
  const int t = threadIdx.x;
  unsigned int s = 0;
  for (int j = 0; j < C; ++j) {
    int i = t * C + j;
    if (i < NBINS) s += hist[i];
  }
  sums[t] = s;
  __syncthreads();
  for (int off = 1; off < 256; off <<= 1) {
    unsigned int v = (t >= off) ? sums[t - off] : 0u;
    __syncthreads();
    sums[t] += v;
    __syncthreads();
  }
  unsigned int base = (t == 0) ? 0u : sums[t - 1];
  for (int j = 0; j < C; ++j) {
    int i = t * C + j;
    if (i < NBINS) {
      unsigned int h = hist[i];
      bin_start[i] = base;
      cursor[i] = base;
      base += h;
    }
  }
  if (t == 255) bin_start[NBINS] = base;  // == TOTE
}

// ---- reorder edges into bins (block-chunked, two-pass, low global-atomic) -
__global__ __launch_bounds__(256) void reorder_kernel(
    const int* __restrict__ rows, const int* __restrict__ cols,
    const float* __restrict__ vals, unsigned int* __restrict__ cursor,
    uint2* __restrict__ sorted) {
  __shared__ unsigned int lcnt[NBINS];
  __shared__ unsigned int lbase[NBINS];
  const int C = (TOTE + RBLOCKS - 1) / RBLOCKS;  // 25000
  const int start = blockIdx.x * C;
  const int end = min(start + C, TOTE);
  for (int i = threadIdx.x; i < NBINS; i += 256) lcnt[i] = 0;
  __syncthreads();
  for (int i = start + threadIdx.x; i < end; i += 256)
    atomicAdd(&lcnt[((unsigned)rows[i]) >> 6], 1u);
  __syncthreads();
  for (int i = threadIdx.x; i < NBINS; i += 256) {
    unsigned int c = lcnt[i];
    if (c) lbase[i] = atomicAdd(&cursor[i], c);
    lcnt[i] = 0;
  }
  __syncthreads();
  for (int i = start + threadIdx.x; i < end; i += 256) {
    unsigned int r = (unsigned)rows[i];
    int bin = r >> 6;
    unsigned int p = lbase[bin] + atomicAdd(&lcnt[bin], 1u);
    int s = i / EE;  // support id (compiler magic-mul)
    unsigned int pack = ((unsigned)cols[i]) | ((r & 63u) << 17) | (((unsigned)s) << 23);
    sorted[p] = make_uint2(pack, __float_as_uint(vals[i]));
  }
}

// ---- fused: LDS-atomic accumulate of G0,G1 + GEMM epilogue + tanh ---------
__global__ __launch_bounds__(512) void fused_kernel(
    const float* __restrict__ feat, const float* __restrict__ W,
    const float* __restrict__ Wc, const uint2* __restrict__ sorted,
    const unsigned int* __restrict__ bin_start, float* __restrict__ out) {
  __shared__ float G[2 * RR * FF];  // exactly 64 KB: G0 then G1, [RR][FF] each
  const int tid = threadIdx.x;

  float4* gz = (float4*)G;
#pragma unroll
  for (int i = 0; i < (2 * RR * FF / 4) / 512; ++i)  // 8 iters
    gz[tid + i * 512] = make_float4(0.f, 0.f, 0.f, 0.f);

  const float c00 = Wc[0], c01 = Wc[1], c10 = Wc[2], c11 = Wc[3];
  const float c20 = Wc[4], c21 = Wc[5], c30 = Wc[6], c31 = Wc[7];
  __syncthreads();

  const int bin = blockIdx.x;
  const unsigned int e0 = bin_start[bin];
  const unsigned int e1 = bin_start[bin + 1];
  const int lane = tid & 63;
  const int wid = tid >> 6;  // 0..7 waves

  // lane l owns feature elements l and l+64 -> 2-way (free) LDS bank pattern
  for (unsigned int e = e0 + wid; e < e1; e += 8) {
    uint2 cv = sorted[e];                    // broadcast 8B load
    float v = __uint_as_float(cv.y);
    int col = cv.x & 0x1FFFF;
    int ro = (cv.x >> 17) & 63;
    int s = cv.x >> 23;
    float w0 = (s == 0) ? c00 : (s == 1) ? c10 : (s == 2) ? c20 : c30;
    float w1 = (s == 0) ? c01 : (s == 1) ? c11 : (s == 2) ? c21 : c31;
    float x0 = feat[col * FF + lane];        // 256B coalesced
    float x1 = feat[col * FF + 64 + lane];   // 256B coalesced
    float v0 = v * w0, v1 = v * w1;
    atomicAdd(&G[ro * FF + lane], v0 * x0);
    atomicAdd(&G[ro * FF + 64 + lane], v0 * x1);
    atomicAdd(&G[RR * FF + ro * FF + lane], v1 * x0);
    atomicAdd(&G[RR * FF + ro * FF + 64 + lane], v1 * x1);
  }
  __syncthreads();

  // GEMM: out[bin*RR + r][o] = tanh(sum_k G0[r][k]*W0[k][o] + G1[r][k]*W1[k][o])
  const int tx = tid & 31;   // output cols tx*4 .. tx*4+3
  const int ty = tid >> 5;   // 0..15 -> rows ty*4 .. ty*4+3
  float acc[4][4];
#pragma unroll
  for (int r = 0; r < 4; ++r)
#pragma unroll
    for (int c = 0; c < 4; ++c) acc[r][c] = 0.f;

  const float* W0 = W;
  const float* W1 = W + FF * OO;
  for (int k = 0; k < FF; ++k) {
    float4 b0 = *(const float4*)&W0[k * OO + tx * 4];
    float4 b1 = *(const float4*)&W1[k * OO + tx * 4];
#pragma unroll
    for (int r = 0; r < 4; ++r) {
      float a0 = G[(ty * 4 + r) * FF + k];
      float a1 = G[RR * FF + (ty * 4 + r) * FF + k];
      acc[r][0] += a0 * b0.x + a1 * b1.x;
      acc[r][1] += a0 * b0.y + a1 * b1.y;
      acc[r][2] += a0 * b0.z + a1 * b1.z;
      acc[r][3] += a0 * b0.w + a1 * b1.w;
    }
  }
#pragma unroll
  for (int r = 0; r < 4; ++r) {
    int row = bin * RR + ty * 4 + r;
    if (row < NN) {
      float4 o;
      o.x = tanhf(acc[r][0]);
      o.y = tanhf(acc[r][1]);
      o.z = tanhf(acc[r][2]);
      o.w = tanhf(acc[r][3]);
      *(float4*)&out[(size_t)row * OO + tx * 4] = o;
    }
  }
}

// ===========================================================================
// FALLBACK PATH (round-1, proven): used only if ws_size is too small
// ===========================================================================
__global__ void compute_V_kernel(const float* __restrict__ W,
                                 const float* __restrict__ Wc,
                                 float* __restrict__ V) {
  int i = blockIdx.x * blockDim.x + threadIdx.x;
  int s = i >> 14;
  int fo = i & 16383;
  V[i] = Wc[s * BBASES + 0] * W[fo] + Wc[s * BBASES + 1] * W[16384 + fo];
}

__global__ __launch_bounds__(256) void scatter_kernel(
    const float* __restrict__ feat, const int* __restrict__ rows,
    const int* __restrict__ cols, const float* __restrict__ vals,
    float* __restrict__ agg) {
  int t = blockIdx.x * blockDim.x + threadIdx.x;
  int e = t >> 5;
  int q = t & 31;
  if (e >= EE) return;
  int r = rows[e];
  int c = cols[e];
  float v = vals[e];
  const float4 x = *reinterpret_cast<const float4*>(&feat[(size_t)c * FF + q * 4]);
  float* dst = &agg[(size_t)r * FF + q * 4];
  unsafeAtomicAdd(dst + 0, v * x.x);
  unsafeAtomicAdd(dst + 1, v * x.y);
  unsafeAtomicAdd(dst + 2, v * x.z);
  unsafeAtomicAdd(dst + 3, v * x.w);
}

__global__ __launch_bounds__(256) void gemm_acc_kernel(
    const float* __restrict__ A, const float* __restrict__ Bv,
    float* __restrict__ C) {
  __shared__ float As[16][64];
  __shared__ float Bs[16][128];
  const int tid = threadIdx.x;
  const int bm0 = blockIdx.x * 64;
  const int tx = tid & 31;
  const int ty = tid >> 5;
  float acc[8][4];
#pragma unroll
  for (int r = 0; r < 8; ++r)
#pragma unroll
    for (int c = 0; c < 4; ++c) acc[r][c] = 0.0f;
  const int ar = tid >> 2;
  const int akq = tid & 3;
  for (int k0 = 0; k0 < FF; k0 += 16) {
    {
      int row = bm0 + ar;
      float4 av = make_float4(0.f, 0.f, 0.f, 0.f);
      if (row < NN)
        av = *reinterpret_cast<const float4*>(&A[(size_t)row * FF + k0 + akq * 4]);
      As[akq * 4 + 0][ar] = av.x;
      As[akq * 4 + 1][ar] = av.y;
      As[akq * 4 + 2][ar] = av.z;
      As[akq * 4 + 3][ar] = av.w;
    }
#pragma unroll
    for (int i = 0; i < 2; ++i) {
      int v = tid + i * 256;
      int kk = v >> 5;
      int cq = v & 31;
      *reinterpret_cast<float4*>(&Bs[kk][cq * 4]) =
          *reinterpret_cast<const float4*>(&Bv[(k0 + kk) * OO + cq * 4]);
    }
    __syncthreads();
#pragma unroll
    for (int kk = 0; kk < 16; ++kk) {
      float4 b = *reinterpret_cast<const float4*>(&Bs[kk][tx * 4]);
#pragma unroll
      for (int r = 0; r < 8; ++r) {
        float a = As[kk][ty * 8 + r];
        acc[r][0] += a * b.x;
        acc[r][1] += a * b.y;
        acc[r][2] += a * b.z;
        acc[r][3] += a * b.w;
      }
    }
    __syncthreads();
  }
#pragma unroll
  for (int r = 0; r < 8; ++r) {
    int row = bm0 + ty * 8 + r;
    if (row < NN) {
      float4* cp = reinterpret_cast<float4*>(&C[(size_t)row * OO + tx * 4]);
      float4 c = *cp;
      c.x += acc[r][0];
      c.y += acc[r][1];
      c.z += acc[r][2];
      c.w += acc[r][3];
      *cp = c;
    }
  }
}

__global__ __launch_bounds__(256) void tanh_kernel(float* __restrict__ out) {
  int i = blockIdx.x * blockDim.x + threadIdx.x;
  float4* p = reinterpret_cast<float4*>(out) + i;
  float4 v = *p;
  v.x = tanhf(v.x);
  v.y = tanhf(v.y);
  v.z = tanhf(v.z);
  v.w = tanhf(v.w);
  *p = v;
}

// ===========================================================================
extern "C" void kernel_launch(void* const* d_in, const int* in_sizes, int n_in,
                              void* d_out, int out_size, void* d_ws,
                              size_t ws_size, hipStream_t stream) {
  const float* feat = (const float*)d_in[0];   // [N, F]
  const float* W = (const float*)d_in[1];      // [B, F, O]
  const float* Wc = (const float*)d_in[2];     // [S, B]
  const int* erows = (const int*)d_in[3];      // [S, E]
  const int* ecols = (const int*)d_in[4];      // [S, E]
  const float* evals = (const float*)d_in[5];  // [S, E]
  float* out = (float*)d_out;                  // [N, O] f32

  unsigned char* ws = (unsigned char*)d_ws;
  unsigned int* hist = (unsigned int*)ws;                 // NBINS
  unsigned int* bin_start = hist + NBINS;                 // NBINS+1
  unsigned int* cursor = bin_start + NBINS + 1;           // NBINS
  size_t sorted_off = (((size_t)(3 * NBINS + 1) * 4) + 255) & ~(size_t)255;
  uint2* sorted = (uint2*)(ws + sorted_off);              // TOTE * 8B
  size_t needed = sorted_off + (size_t)TOTE * 8;

  if (ws_size >= needed) {
    hipMemsetAsync(hist, 0, (size_t)NBINS * 4, stream);
    hist_kernel<<<RBLOCKS, 256, 0, stream>>>(erows, hist);
    scan_kernel<<<1, 256, 0, stream>>>(hist, bin_start, cursor);
    reorder_kernel<<<RBLOCKS, 256, 0, stream>>>(erows, ecols, evals, cursor, sorted);
    fused_kernel<<<NBINS, 512, 0, stream>>>(feat, W, Wc, sorted, bin_start, out);
  } else {
    // fallback: round-1 path (needs ~51.5 MB ws)
    float* V = (float*)d_ws;
    float* agg = V + (size_t)SS * FF * OO;
    compute_V_kernel<<<(SS * FF * OO) / 256, 256, 0, stream>>>(W, Wc, V);
    hipMemsetAsync(out, 0, (size_t)NN * OO * sizeof(float), stream);
    for (int s = 0; s < SS; ++s) {
      hipMemsetAsync(agg, 0, (size_t)NN * FF * sizeof(float), stream);
      scatter_kernel<<<(EE * 32) / 256, 256, 0, stream>>>(
          feat, erows + (size_t)s * EE, ecols + (size_t)s * EE,
          evals + (size_t)s * EE, agg);
      gemm_acc_kernel<<<(NN + 63) / 64, 256, 0, stream>>>(
          agg, V + (size_t)s * FF * OO, out);
    }
    tanh_kernel<<<(NN * OO / 4) / 256, 256, 0, stream>>>(out);
  }
}

// Round 3
// 17634.354 us; speedup vs baseline: 1.2235x; 1.0707x over previous
//
#include <hip/hip_runtime.h>
#include <hip/hip_bf16.h>

// Problem constants: N=100000, F=128, O=128, S=4, B=2, E=3200000
#define NN 100000
#define FF 128
#define OO 128
#define SS 4
#define BBASES 2
#define EE 3200000
#define TOTE (SS * EE)               // 12.8M edges total
#define RR 32                        // dest rows per bin
#define RSHIFT 5
#define NBINS ((NN + RR - 1) / RR)   // 3125
#define RBLOCKS 512                  // blocks for hist/reorder

// ===========================================================================
// out[n] = tanh( G0[n] @ W0 + G1[n] @ W1 ),
// G_b[n] = sum_s Wc[s,b] * sum_{e in support s: row_e=n} val_e * feat[col_e]
// Edges binned by dest row (32 rows/bin); one block per bin accumulates G0,G1
// in LDS (ds_add_f32), then runs the 32x128x(128x2) GEMM + tanh epilogue.
// ===========================================================================

// ---- histogram of edges per bin -------------------------------------------
__global__ __launch_bounds__(256) void hist_kernel(const int* __restrict__ rows,
                                                   unsigned int* __restrict__ hist) {
  __shared__ unsigned int lh[NBINS];
  for (int i = threadIdx.x; i < NBINS; i += 256) lh[i] = 0;
  __syncthreads();
  const int stride = gridDim.x * 256;
  for (int i = blockIdx.x * 256 + threadIdx.x; i < TOTE; i += stride)
    atomicAdd(&lh[((unsigned)rows[i]) >> RSHIFT], 1u);
  __syncthreads();
  for (int i = threadIdx.x; i < NBINS; i += 256) {
    unsigned int c = lh[i];
    if (c) atomicAdd(&hist[i], c);
  }
}

// ---- exclusive scan over NBINS (single block) -----------------------------
__global__ __launch_bounds__(256) void scan_kernel(const unsigned int* __restrict__ hist,
                                                   unsigned int* __restrict__ bin_start,
                                                   unsigned int* __restrict__ cursor) {
  __shared__ unsigned int sums[256];
  const int C = (NBINS + 255) / 256;  // 13
  const int t = threadIdx.x;
  unsigned int s = 0;
  for (int j = 0; j < C; ++j) {
    int i = t * C + j;
    if (i < NBINS) s += hist[i];
  }
  sums[t] = s;
  __syncthreads();
  for (int off = 1; off < 256; off <<= 1) {
    unsigned int v = (t >= off) ? sums[t - off] : 0u;
    __syncthreads();
    sums[t] += v;
    __syncthreads();
  }
  unsigned int base = (t == 0) ? 0u : sums[t - 1];
  for (int j = 0; j < C; ++j) {
    int i = t * C + j;
    if (i < NBINS) {
      unsigned int h = hist[i];
      bin_start[i] = base;
      cursor[i] = base;
      base += h;
    }
  }
  if (t == 255) bin_start[NBINS] = base;  // == TOTE
}

// ---- reorder edges into bins ----------------------------------------------
__global__ __launch_bounds__(256) void reorder_kernel(
    const int* __restrict__ rows, const int* __restrict__ cols,
    const float* __restrict__ vals, unsigned int* __restrict__ cursor,
    uint2* __restrict__ sorted) {
  __shared__ unsigned int lcnt[NBINS];
  __shared__ unsigned int lbase[NBINS];
  const int C = (TOTE + RBLOCKS - 1) / RBLOCKS;  // 25000
  const int start = blockIdx.x * C;
  const int end = min(start + C, TOTE);
  for (int i = threadIdx.x; i < NBINS; i += 256) lcnt[i] = 0;
  __syncthreads();
  for (int i = start + threadIdx.x; i < end; i += 256)
    atomicAdd(&lcnt[((unsigned)rows[i]) >> RSHIFT], 1u);
  __syncthreads();
  for (int i = threadIdx.x; i < NBINS; i += 256) {
    unsigned int c = lcnt[i];
    if (c) lbase[i] = atomicAdd(&cursor[i], c);
    lcnt[i] = 0;
  }
  __syncthreads();
  for (int i = start + threadIdx.x; i < end; i += 256) {
    unsigned int r = (unsigned)rows[i];
    int bin = r >> RSHIFT;
    unsigned int p = lbase[bin] + atomicAdd(&lcnt[bin], 1u);
    int s = i / EE;  // support id
    unsigned int pack = ((unsigned)cols[i]) | ((r & (RR - 1u)) << 17) |
                        (((unsigned)s) << 22);
    sorted[p] = make_uint2(pack, __float_as_uint(vals[i]));
  }
}

// ---- fused: LDS accumulate (4-edge unrolled) + GEMM + tanh ----------------
__global__ __launch_bounds__(256) void fused_kernel(
    const float* __restrict__ feat, const float* __restrict__ W,
    const float* __restrict__ Wc, const uint2* __restrict__ sorted,
    const unsigned int* __restrict__ bin_start, float* __restrict__ out) {
  __shared__ float G[2 * RR * FF];  // 32 KB: G0 then G1, [RR][FF] each
  const int tid = threadIdx.x;

  float4* gz = (float4*)G;
#pragma unroll
  for (int i = 0; i < (2 * RR * FF / 4) / 256; ++i)  // 8 iters
    gz[tid + i * 256] = make_float4(0.f, 0.f, 0.f, 0.f);

  const float c00 = Wc[0], c01 = Wc[1], c10 = Wc[2], c11 = Wc[3];
  const float c20 = Wc[4], c21 = Wc[5], c30 = Wc[6], c31 = Wc[7];
  __syncthreads();

  const int bin = blockIdx.x;
  const unsigned int e0 = bin_start[bin];
  const unsigned int e1 = bin_start[bin + 1];
  const int lane = tid & 63;
  const int wid = tid >> 6;  // 0..3 waves

  // lane l owns feature elements l and l+64 (2-way LDS bank alias = free).
  // 4 edges per wave-iteration: 4 sorted loads, then 8 independent 256B
  // gathers in flight, then 16 ds_add_f32.
  unsigned int base = e0 + (wid << 2);
  for (; base + 4 <= e1; base += 16) {
    uint2 cv[4];
#pragma unroll
    for (int j = 0; j < 4; ++j) cv[j] = sorted[base + j];
    float x0[4], x1[4];
#pragma unroll
    for (int j = 0; j < 4; ++j) {
      int col = cv[j].x & 0x1FFFF;
      x0[j] = feat[(col << 7) + lane];
      x1[j] = feat[(col << 7) + 64 + lane];
    }
    float v0[4], v1[4];
    int ro[4];
#pragma unroll
    for (int j = 0; j < 4; ++j) {
      float v = __uint_as_float(cv[j].y);
      int s = cv[j].x >> 22;
      float w0 = (s == 0) ? c00 : (s == 1) ? c10 : (s == 2) ? c20 : c30;
      float w1 = (s == 0) ? c01 : (s == 1) ? c11 : (s == 2) ? c21 : c31;
      v0[j] = v * w0;
      v1[j] = v * w1;
      ro[j] = (cv[j].x >> 17) & (RR - 1);
    }
#pragma unroll
    for (int j = 0; j < 4; ++j) {
      int g0 = (ro[j] << 7) + lane;
      atomicAdd(&G[g0], v0[j] * x0[j]);
      atomicAdd(&G[g0 + 64], v0[j] * x1[j]);
      atomicAdd(&G[RR * FF + g0], v1[j] * x0[j]);
      atomicAdd(&G[RR * FF + g0 + 64], v1[j] * x1[j]);
    }
  }
  // tail: <4 edges for this wave
  for (unsigned int e = base; e < e1 && e < base + 4; ++e) {
    uint2 cv = sorted[e];
    float v = __uint_as_float(cv.y);
    int col = cv.x & 0x1FFFF;
    int ro1 = (cv.x >> 17) & (RR - 1);
    int s = cv.x >> 22;
    float w0 = (s == 0) ? c00 : (s == 1) ? c10 : (s == 2) ? c20 : c30;
    float w1 = (s == 0) ? c01 : (s == 1) ? c11 : (s == 2) ? c21 : c31;
    float xa = feat[(col << 7) + lane];
    float xb = feat[(col << 7) + 64 + lane];
    int g0 = (ro1 << 7) + lane;
    atomicAdd(&G[g0], v * w0 * xa);
    atomicAdd(&G[g0 + 64], v * w0 * xb);
    atomicAdd(&G[RR * FF + g0], v * w1 * xa);
    atomicAdd(&G[RR * FF + g0 + 64], v * w1 * xb);
  }
  __syncthreads();

  // GEMM epilogue: out[bin*RR + r][o] = tanh(sum_k G0[r][k]W0[k][o] + G1[r][k]W1[k][o])
  const int tx = tid & 31;   // output cols tx*4 .. tx*4+3
  const int ty = tid >> 5;   // 0..7 -> rows ty*4 .. ty*4+3
  float acc[4][4];
#pragma unroll
  for (int r = 0; r < 4; ++r)
#pragma unroll
    for (int c = 0; c < 4; ++c) acc[r][c] = 0.f;

  const float* W0 = W;
  const float* W1 = W + FF * OO;
  for (int k = 0; k < FF; ++k) {
    float4 b0 = *(const float4*)&W0[k * OO + tx * 4];
    float4 b1 = *(const float4*)&W1[k * OO + tx * 4];
#pragma unroll
    for (int r = 0; r < 4; ++r) {
      float a0 = G[(ty * 4 + r) * FF + k];
      float a1 = G[RR * FF + (ty * 4 + r) * FF + k];
      acc[r][0] += a0 * b0.x + a1 * b1.x;
      acc[r][1] += a0 * b0.y + a1 * b1.y;
      acc[r][2] += a0 * b0.z + a1 * b1.z;
      acc[r][3] += a0 * b0.w + a1 * b1.w;
    }
  }
#pragma unroll
  for (int r = 0; r < 4; ++r) {
    int row = bin * RR + ty * 4 + r;  // N divisible by RR: no bounds check
    float4 o;
    o.x = tanhf(acc[r][0]);
    o.y = tanhf(acc[r][1]);
    o.z = tanhf(acc[r][2]);
    o.w = tanhf(acc[r][3]);
    *(float4*)&out[(size_t)row * OO + tx * 4] = o;
  }
}

// ===========================================================================
// FALLBACK PATH (round-1, proven): used only if ws_size is too small
// ===========================================================================
__global__ void compute_V_kernel(const float* __restrict__ W,
                                 const float* __restrict__ Wc,
                                 float* __restrict__ V) {
  int i = blockIdx.x * blockDim.x + threadIdx.x;
  int s = i >> 14;
  int fo = i & 16383;
  V[i] = Wc[s * BBASES + 0] * W[fo] + Wc[s * BBASES + 1] * W[16384 + fo];
}

__global__ __launch_bounds__(256) void scatter_kernel(
    const float* __restrict__ feat, const int* __restrict__ rows,
    const int* __restrict__ cols, const float* __restrict__ vals,
    float* __restrict__ agg) {
  int t = blockIdx.x * blockDim.x + threadIdx.x;
  int e = t >> 5;
  int q = t & 31;
  if (e >= EE) return;
  int r = rows[e];
  int c = cols[e];
  float v = vals[e];
  const float4 x = *reinterpret_cast<const float4*>(&feat[(size_t)c * FF + q * 4]);
  float* dst = &agg[(size_t)r * FF + q * 4];
  unsafeAtomicAdd(dst + 0, v * x.x);
  unsafeAtomicAdd(dst + 1, v * x.y);
  unsafeAtomicAdd(dst + 2, v * x.z);
  unsafeAtomicAdd(dst + 3, v * x.w);
}

__global__ __launch_bounds__(256) void gemm_acc_kernel(
    const float* __restrict__ A, const float* __restrict__ Bv,
    float* __restrict__ C) {
  __shared__ float As[16][64];
  __shared__ float Bs[16][128];
  const int tid = threadIdx.x;
  const int bm0 = blockIdx.x * 64;
  const int tx = tid & 31;
  const int ty = tid >> 5;
  float acc[8][4];
#pragma unroll
  for (int r = 0; r < 8; ++r)
#pragma unroll
    for (int c = 0; c < 4; ++c) acc[r][c] = 0.0f;
  const int ar = tid >> 2;
  const int akq = tid & 3;
  for (int k0 = 0; k0 < FF; k0 += 16) {
    {
      int row = bm0 + ar;
      float4 av = make_float4(0.f, 0.f, 0.f, 0.f);
      if (row < NN)
        av = *reinterpret_cast<const float4*>(&A[(size_t)row * FF + k0 + akq * 4]);
      As[akq * 4 + 0][ar] = av.x;
      As[akq * 4 + 1][ar] = av.y;
      As[akq * 4 + 2][ar] = av.z;
      As[akq * 4 + 3][ar] = av.w;
    }
#pragma unroll
    for (int i = 0; i < 2; ++i) {
      int v = tid + i * 256;
      int kk = v >> 5;
      int cq = v & 31;
      *reinterpret_cast<float4*>(&Bs[kk][cq * 4]) =
          *reinterpret_cast<const float4*>(&Bv[(k0 + kk) * OO + cq * 4]);
    }
    __syncthreads();
#pragma unroll
    for (int kk = 0; kk < 16; ++kk) {
      float4 b = *reinterpret_cast<const float4*>(&Bs[kk][tx * 4]);
#pragma unroll
      for (int r = 0; r < 8; ++r) {
        float a = As[kk][ty * 8 + r];
        acc[r][0] += a * b.x;
        acc[r][1] += a * b.y;
        acc[r][2] += a * b.z;
        acc[r][3] += a * b.w;
      }
    }
    __syncthreads();
  }
#pragma unroll
  for (int r = 0; r < 8; ++r) {
    int row = bm0 + ty * 8 + r;
    if (row < NN) {
      float4* cp = reinterpret_cast<float4*>(&C[(size_t)row * OO + tx * 4]);
      float4 c = *cp;
      c.x += acc[r][0];
      c.y += acc[r][1];
      c.z += acc[r][2];
      c.w += acc[r][3];
      *cp = c;
    }
  }
}

__global__ __launch_bounds__(256) void tanh_kernel(float* __restrict__ out) {
  int i = blockIdx.x * blockDim.x + threadIdx.x;
  float4* p = reinterpret_cast<float4*>(out) + i;
  float4 v = *p;
  v.x = tanhf(v.x);
  v.y = tanhf(v.y);
  v.z = tanhf(v.z);
  v.w = tanhf(v.w);
  *p = v;
}

// ===========================================================================
extern "C" void kernel_launch(void* const* d_in, const int* in_sizes, int n_in,
                              void* d_out, int out_size, void* d_ws,
                              size_t ws_size, hipStream_t stream) {
  const float* feat = (const float*)d_in[0];   // [N, F]
  const float* W = (const float*)d_in[1];      // [B, F, O]
  const float* Wc = (const float*)d_in[2];     // [S, B]
  const int* erows = (const int*)d_in[3];      // [S, E]
  const int* ecols = (const int*)d_in[4];      // [S, E]
  const float* evals = (const float*)d_in[5];  // [S, E]
  float* out = (float*)d_out;                  // [N, O] f32

  unsigned char* ws = (unsigned char*)d_ws;
  unsigned int* hist = (unsigned int*)ws;                 // NBINS
  unsigned int* bin_start = hist + NBINS;                 // NBINS+1
  unsigned int* cursor = bin_start + NBINS + 1;           // NBINS
  size_t sorted_off = (((size_t)(3 * NBINS + 1) * 4) + 255) & ~(size_t)255;
  uint2* sorted = (uint2*)(ws + sorted_off);              // TOTE * 8B
  size_t needed = sorted_off + (size_t)TOTE * 8;

  if (ws_size >= needed) {
    hipMemsetAsync(hist, 0, (size_t)NBINS * 4, stream);
    hist_kernel<<<RBLOCKS, 256, 0, stream>>>(erows, hist);
    scan_kernel<<<1, 256, 0, stream>>>(hist, bin_start, cursor);
    reorder_kernel<<<RBLOCKS, 256, 0, stream>>>(erows, ecols, evals, cursor, sorted);
    fused_kernel<<<NBINS, 256, 0, stream>>>(feat, W, Wc, sorted, bin_start, out);
  } else {
    float* V = (float*)d_ws;
    float* agg = V + (size_t)SS * FF * OO;
    compute_V_kernel<<<(SS * FF * OO) / 256, 256, 0, stream>>>(W, Wc, V);
    hipMemsetAsync(out, 0, (size_t)NN * OO * sizeof(float), stream);
    for (int s = 0; s < SS; ++s) {
      hipMemsetAsync(agg, 0, (size_t)NN * FF * sizeof(float), stream);
      scatter_kernel<<<(EE * 32) / 256, 256, 0, stream>>>(
          feat, erows + (size_t)s * EE, ecols + (size_t)s * EE,
          evals + (size_t)s * EE, agg);
      gemm_acc_kernel<<<(NN + 63) / 64, 256, 0, stream>>>(
          agg, V + (size_t)s * FF * OO, out);
    }
    tanh_kernel<<<(NN * OO / 4) / 256, 256, 0, stream>>>(out);
  }
}